// Round 1
// baseline (711.372 us; speedup 1.0000x reference)
//
#include <hip/hip_runtime.h>

#define Bn 16
#define Cn 256
#define Tn 8192
#define TFn 512
#define HIDn 256
#define HEADSn 8
#define HDn 32
#define T2n (Tn/2)
#define TW 64

// ws float layout:
//  g   [Bn][Cn]                 off 0
//  hh  [Bn][Cn]                 off Bn*Cn
//  qkw [Bn][HEADSn][Cn]         off 2*Bn*Cn
//  qkb [Bn][HEADSn]             off 2*Bn*Cn + Bn*HEADSn*Cn

__global__ __launch_bounds__(256)
void prep_kernel(const float* __restrict__ temb,
                 const float* __restrict__ ln_w, const float* __restrict__ ln_b,
                 const float* __restrict__ ss_w, const float* __restrict__ ss_b,
                 const float* __restrict__ kv_w, const float* __restrict__ kv_b,
                 const float* __restrict__ qw,  const float* __restrict__ qt_w,
                 const float* __restrict__ qt_b, float* __restrict__ ws)
{
    const int b = blockIdx.x, tid = threadIdx.x;
    __shared__ float st[TFn];
    __shared__ float qbs[HIDn];
    for (int i = tid; i < TFn; i += 256) {
        float v = temb[b*TFn + i];
        st[i] = v / (1.f + __expf(-v));   // silu
    }
    __syncthreads();
    const float4* stv = (const float4*)st;
    const float4* wS = (const float4*)(ss_w + (size_t)tid*TFn);
    const float4* wC = (const float4*)(ss_w + (size_t)(Cn+tid)*TFn);
    const float4* wQ = (const float4*)(qt_w + (size_t)tid*TFn);
    float aS=0.f, aC=0.f, aQ=0.f;
    for (int k = 0; k < TFn/4; ++k) {
        float4 s = stv[k], a = wS[k], c = wC[k], q4 = wQ[k];
        aS += s.x*a.x + s.y*a.y + s.z*a.z + s.w*a.w;
        aC += s.x*c.x + s.y*c.y + s.z*c.z + s.w*c.w;
        aQ += s.x*q4.x + s.y*q4.y + s.z*q4.z + s.w*q4.w;
    }
    float shift = aS + ss_b[tid];
    float scale = aC + ss_b[Cn + tid];
    float qb = qw[tid] + aQ + qt_b[tid];
    qbs[tid] = qb;
    float sc1 = 1.f + scale;
    ws[b*Cn + tid]         = ln_w[tid] * sc1;                 // g
    ws[Bn*Cn + b*Cn + tid] = ln_b[tid] * sc1 + shift;         // hh
    __syncthreads();
    // qkw[b][h][c] = sum_d qb[h*32+d] * kv_w[h*32+d][c]   (K-half rows 0..255)
    float* qkw = ws + 2*Bn*Cn + b*HEADSn*Cn;
    for (int idx = tid; idx < HEADSn*Cn; idx += 256) {
        int h = idx >> 8, c = idx & 255;
        float acc = 0.f;
        #pragma unroll
        for (int d = 0; d < HDn; ++d)
            acc += qbs[h*HDn + d] * kv_w[(size_t)(h*HDn + d)*Cn + c];
        qkw[idx] = acc;
    }
    if (tid < HEADSn) {
        float acc = 0.f;
        #pragma unroll
        for (int d = 0; d < HDn; ++d) acc += qbs[tid*HDn + d]*kv_b[tid*HDn + d];
        ws[2*Bn*Cn + Bn*HEADSn*Cn + b*HEADSn + tid] = acc;
    }
}

__global__ __launch_bounds__(256)
void qna_main(const float* __restrict__ x,
              const float* __restrict__ kv_w, const float* __restrict__ kv_b,
              const float* __restrict__ rpe,
              const float* __restrict__ proj_w, const float* __restrict__ proj_b,
              const float* __restrict__ ws, float* __restrict__ out)
{
    __shared__ float xs[Cn][TW];            // 64 KB; reused as o_s[256][32] after V-GEMM
    __shared__ float wl[Cn][TW];            // 64 KB weight chunk (XOR-swizzled)
    __shared__ float qkw_s[HEADSn][Cn];     // 8 KB
    __shared__ float gml[Cn], hml[Cn], vbs[Cn];
    __shared__ float lg[HEADSn][TW];
    __shared__ float aw[HEADSn][TW];
    __shared__ float red1[4][64], red2[4][64];
    __shared__ float ms[64], is_[64];
    __shared__ float rpes[HEADSn][2];
    __shared__ float qkbs[HEADSn];

    const int tid = threadIdx.x;
    const int bt  = blockIdx.x;   // t-tile, 0..127
    const int b   = blockIdx.y;

    // ---- phase 0: per-batch params ----
    gml[tid] = ws[b*Cn + tid];
    hml[tid] = ws[Bn*Cn + b*Cn + tid];
    vbs[tid] = kv_b[HIDn + tid];
    {
        const float* qk = ws + 2*Bn*Cn + b*HEADSn*Cn;
        for (int i = tid; i < HEADSn*Cn; i += 256) (&qkw_s[0][0])[i] = qk[i];
    }
    if (tid < HEADSn*2) rpes[tid>>1][tid&1] = rpe[tid];
    if (tid >= 32 && tid < 32+HEADSn)
        qkbs[tid-32] = ws[2*Bn*Cn + Bn*HEADSn*Cn + b*HEADSn + (tid-32)];

    // ---- phase 1: stage x tile [256 c][64 t] ----
    {
        const float* xb = x + (size_t)b*Cn*Tn + (size_t)bt*TW;
        int tl4 = (tid & 15) * 4, cg = tid >> 4;
        for (int c = cg; c < Cn; c += 16)
            *(float4*)&xs[c][tl4] = *(const float4*)&xb[(size_t)c*Tn + tl4];
    }
    __syncthreads();

    // ---- phase 2: LN stats over c, 4 partial sums per t ----
    {
        int t = tid & 63, part = tid >> 6;
        float s = 0.f, sq = 0.f;
        for (int cc = 0; cc < 64; ++cc) {
            float v = xs[part*64 + cc][t];
            s += v; sq += v*v;
        }
        red1[part][t] = s; red2[part][t] = sq;
    }
    __syncthreads();
    if (tid < 64) {
        float s  = red1[0][tid]+red1[1][tid]+red1[2][tid]+red1[3][tid];
        float sq = red2[0][tid]+red2[1][tid]+red2[2][tid]+red2[3][tid];
        float mean = s * (1.f/Cn);
        float var  = sq * (1.f/Cn) - mean*mean;
        ms[tid]  = mean;
        is_[tid] = rsqrtf(var + 1e-6f);
    }
    __syncthreads();

    // ---- phase 3: normalize + FiLM in place ----
    {
        int tl = tid & 63, cg = tid >> 6;
        float mu = ms[tl], iv = is_[tl];
        for (int c = cg; c < Cn; c += 4)
            xs[c][tl] = (xs[c][tl] - mu) * iv * gml[c] + hml[c];
    }
    __syncthreads();

    // ---- phase 4: logits via query-folded weights (2 heads / thread) ----
    {
        int t = tid & 63, grp = tid >> 6;
        float l0 = 0.f, l1 = 0.f;
        for (int c = 0; c < Cn; ++c) {
            float xv = xs[c][t];
            l0 += xv * qkw_s[grp][c];
            l1 += xv * qkw_s[grp+4][c];
        }
        lg[grp][t]   = l0;
        lg[grp+4][t] = l1;
    }
    __syncthreads();

    // ---- phase 5: pairwise softmax (K=2) ----
    {
        int h = tid >> 5, t2 = tid & 31;
        const float sc = 0.17677669529663687f;   // 1/sqrt(32)
        float l0 = (lg[h][2*t2]   + qkbs[h]) * sc + rpes[h][0];
        float l1 = (lg[h][2*t2+1] + qkbs[h]) * sc + rpes[h][1];
        float m = fmaxf(l0, l1);
        float e0 = __expf(l0 - m), e1 = __expf(l1 - m);
        float inv = 1.f / (e0 + e1);
        aw[h][2*t2]   = e0 * inv;
        aw[h][2*t2+1] = e1 * inv;
    }

    // ---- phase 6: V-GEMM  vv[d][t] = sum_c Wv[d][c]*xm[c][t] ----
    float acc[8][8];
    #pragma unroll
    for (int i = 0; i < 8; ++i)
        #pragma unroll
        for (int j = 0; j < 8; ++j) acc[i][j] = 0.f;
    const int d0 = (tid >> 3) << 3;
    const int t0 = (tid & 7) << 3;
    const int g4 = ((d0 >> 3) & 7) << 2;     // float4-granular XOR swizzle key
    const float* Wv = kv_w + (size_t)HIDn * Cn;   // V rows 256..511
    for (int cc = 0; cc < Cn; cc += 64) {
        __syncthreads();
        {
            int ci4 = (tid & 15)*4, dg = tid >> 4;
            for (int d = dg; d < Cn; d += 16)
                *(float4*)&wl[d][ci4 ^ ((((d>>3)&7))<<2)] =
                    *(const float4*)&Wv[(size_t)d*Cn + cc + ci4];
        }
        __syncthreads();
        for (int ci = 0; ci < 64; ++ci) {
            float4 xa  = *(const float4*)&xs[cc+ci][t0];
            float4 xb4 = *(const float4*)&xs[cc+ci][t0+4];
            float xv[8] = {xa.x,xa.y,xa.z,xa.w,xb4.x,xb4.y,xb4.z,xb4.w};
            int ciw = ci ^ g4;
            #pragma unroll
            for (int i = 0; i < 8; ++i) {
                float w = wl[d0+i][ciw];
                #pragma unroll
                for (int j = 0; j < 8; ++j) acc[i][j] += w * xv[j];
            }
        }
    }
    __syncthreads();   // all xs/wl readers done

    // ---- phase 7: attention-weight V, write o into xs region ----
    float* o_s = &xs[0][0];   // [256][32]
    {
        int t2b = t0 >> 1;
        #pragma unroll
        for (int i = 0; i < 8; ++i) {
            int d = d0 + i, h = d >> 5;
            float vb = vbs[d];
            #pragma unroll
            for (int k = 0; k < 4; ++k) {
                float a0 = aw[h][t0 + 2*k], a1 = aw[h][t0 + 2*k + 1];
                o_s[d*32 + t2b + k] = a0*(acc[i][2*k] + vb) + a1*(acc[i][2*k+1] + vb);
            }
        }
    }

    // ---- phase 8: proj GEMM  out[e][t2] = sum_d P[e][d]*o[d][t2] ----
    float acc2[8][4];
    #pragma unroll
    for (int i = 0; i < 8; ++i)
        #pragma unroll
        for (int j = 0; j < 4; ++j) acc2[i][j] = 0.f;
    const int q0 = (tid & 7) << 2;
    for (int dd = 0; dd < Cn; dd += 64) {
        __syncthreads();
        {
            int di4 = (tid & 15)*4, eg = tid >> 4;
            for (int e = eg; e < Cn; e += 16)
                *(float4*)&wl[e][di4 ^ ((((e>>3)&7))<<2)] =
                    *(const float4*)&proj_w[(size_t)e*Cn + dd + di4];
        }
        __syncthreads();
        for (int di = 0; di < 64; ++di) {
            float4 ov = *(const float4*)&o_s[(dd+di)*32 + q0];
            int diw = di ^ g4;
            #pragma unroll
            for (int i = 0; i < 8; ++i) {
                float w = wl[d0+i][diw];
                acc2[i][0] += w*ov.x; acc2[i][1] += w*ov.y;
                acc2[i][2] += w*ov.z; acc2[i][3] += w*ov.w;
            }
        }
    }

    // ---- epilogue: bias + store ----
    {
        int t2g = bt*32 + q0;
        #pragma unroll
        for (int i = 0; i < 8; ++i) {
            int e = d0 + i;
            float pb = proj_b[e];
            float4 r;
            r.x = acc2[i][0]+pb; r.y = acc2[i][1]+pb;
            r.z = acc2[i][2]+pb; r.w = acc2[i][3]+pb;
            *(float4*)&out[((size_t)b*HIDn + e)*T2n + t2g] = r;
        }
    }
}

extern "C" void kernel_launch(void* const* d_in, const int* in_sizes, int n_in,
                              void* d_out, int out_size, void* d_ws, size_t ws_size,
                              hipStream_t stream) {
    (void)in_sizes; (void)n_in; (void)out_size; (void)ws_size;
    const float* x      = (const float*)d_in[0];
    const float* temb   = (const float*)d_in[1];
    const float* ln_w   = (const float*)d_in[2];
    const float* ln_b   = (const float*)d_in[3];
    const float* ss_w   = (const float*)d_in[4];
    const float* ss_b   = (const float*)d_in[5];
    const float* kv_w   = (const float*)d_in[6];
    const float* kv_b   = (const float*)d_in[7];
    const float* q      = (const float*)d_in[8];
    const float* qt_w   = (const float*)d_in[9];
    const float* qt_b   = (const float*)d_in[10];
    const float* rpe    = (const float*)d_in[11];
    const float* proj_w = (const float*)d_in[12];
    const float* proj_b = (const float*)d_in[13];
    float* ws  = (float*)d_ws;
    float* out = (float*)d_out;

    prep_kernel<<<dim3(Bn), dim3(256), 0, stream>>>(
        temb, ln_w, ln_b, ss_w, ss_b, kv_w, kv_b, q, qt_w, qt_b, ws);
    qna_main<<<dim3(Tn/TW, Bn), dim3(256), 0, stream>>>(
        x, kv_w, kv_b, rpe, proj_w, proj_b, ws, out);
}

// Round 4
// 173.939 us; speedup vs baseline: 4.0898x; 4.0898x over previous
//
#include <hip/hip_runtime.h>
#include <hip/hip_bf16.h>

#define Bn 16
#define Cn 256
#define Tn 8192
#define TFn 512
#define HIDn 256
#define HEADSn 8
#define HDn 32
#define T2n (Tn/2)
#define TW 64
#define XPAD 264   // bf16 row stride: 528 B = 132 dwords ≡ 4 (mod 32) -> balanced banks

// ws float-index layout:
//   WS_G    g[16][256]
//   WS_H    hh[16][256]
//   WS_QKB  qkb[16][8]
//   WS_BF16 (as __bf16*): qkwB[16][16][256] | WvB[256][256] | projB[256][256]
#define WS_G 0
#define WS_H 4096
#define WS_QKB 8192
#define WS_BF16 8320

typedef __attribute__((ext_vector_type(8))) __bf16 bf16x8;
typedef __attribute__((ext_vector_type(4))) __bf16 bf16x4;
typedef __attribute__((ext_vector_type(4))) float f32x4;

__global__ __launch_bounds__(256)
void prep_kernel(const float* __restrict__ temb,
                 const float* __restrict__ ln_w, const float* __restrict__ ln_b,
                 const float* __restrict__ ss_w, const float* __restrict__ ss_b,
                 const float* __restrict__ kv_w, const float* __restrict__ kv_b,
                 const float* __restrict__ qw,  const float* __restrict__ qt_w,
                 const float* __restrict__ qt_b, const float* __restrict__ proj_w,
                 float* __restrict__ ws)
{
    __bf16* bfr = (__bf16*)(ws + WS_BF16);
    const int tid = threadIdx.x;

    if (blockIdx.x >= Bn) {
        // ---- weight bf16 conversion: Wv (kv_w rows 256..511) then proj_w ----
        int cb = blockIdx.x - Bn;                       // 0..63
        size_t base = (size_t)cb*2048 + (size_t)tid*8;  // 64*2048 = 131072 elements
        const float* src = (base < 65536) ? (kv_w + 65536 + base)
                                          : (proj_w + (base - 65536));
        __bf16* dst = bfr + 65536 + base;               // WvB @65536, projB @131072
        bf16x8 o;
        #pragma unroll
        for (int i = 0; i < 8; ++i) o[i] = (__bf16)src[i];
        *(bf16x8*)dst = o;
        return;
    }

    const int b = blockIdx.x;
    __shared__ float st[TFn];
    __shared__ float qbs[HIDn];
    for (int i = tid; i < TFn; i += 256) {
        float v = temb[b*TFn + i];
        st[i] = v / (1.f + __expf(-v));   // silu
    }
    __syncthreads();
    const float4* stv = (const float4*)st;
    const float4* wS = (const float4*)(ss_w + (size_t)tid*TFn);
    const float4* wC = (const float4*)(ss_w + (size_t)(Cn+tid)*TFn);
    const float4* wQ = (const float4*)(qt_w + (size_t)tid*TFn);
    float aS=0.f, aC=0.f, aQ=0.f;
    for (int k = 0; k < TFn/4; ++k) {
        float4 s = stv[k], a = wS[k], c = wC[k], q4 = wQ[k];
        aS += s.x*a.x + s.y*a.y + s.z*a.z + s.w*a.w;
        aC += s.x*c.x + s.y*c.y + s.z*c.z + s.w*c.w;
        aQ += s.x*q4.x + s.y*q4.y + s.z*q4.z + s.w*q4.w;
    }
    float shift = aS + ss_b[tid];
    float scale = aC + ss_b[Cn + tid];
    float qb = qw[tid] + aQ + qt_b[tid];
    qbs[tid] = qb;
    float sc1 = 1.f + scale;
    ws[WS_G + b*Cn + tid] = ln_w[tid] * sc1;                 // g
    ws[WS_H + b*Cn + tid] = ln_b[tid] * sc1 + shift;         // hh
    __syncthreads();
    // qkwB[b][h][c] bf16, rows 8..15 zero-padded for MFMA M=16
    __bf16* qkwB = bfr + b*16*Cn;
    for (int idx = tid; idx < 16*Cn; idx += 256) {
        int h = idx >> 8, c = idx & 255;
        float acc = 0.f;
        if (h < HEADSn) {
            #pragma unroll
            for (int d = 0; d < HDn; ++d)
                acc += qbs[h*HDn + d] * kv_w[(size_t)(h*HDn + d)*Cn + c];
        }
        qkwB[idx] = (__bf16)acc;
    }
    if (tid < HEADSn) {
        float acc = 0.f;
        #pragma unroll
        for (int d = 0; d < HDn; ++d) acc += qbs[tid*HDn + d]*kv_b[tid*HDn + d];
        ws[WS_QKB + b*HEADSn + tid] = acc;
    }
}

__global__ __launch_bounds__(256, 2)
void qna_main(const float* __restrict__ x,
              const float* __restrict__ kv_b, const float* __restrict__ rpe,
              const float* __restrict__ proj_b,
              const float* __restrict__ ws, float* __restrict__ out)
{
    __shared__ __bf16 xmT[TW][XPAD];    // 33792 B: xm transposed [t][c]
    __shared__ __bf16 oT[32][XPAD];     // 16896 B: o transposed [t2][d]
    __shared__ float gml[Cn], hml[Cn], vbs[Cn], pbs[Cn];
    __shared__ float red1[4][64], red2[4][64];
    __shared__ float ms[64], is_[64];
    __shared__ float lg[HEADSn][TW];
    __shared__ float aw[HEADSn][TW];
    __shared__ float rpes[HEADSn][2];
    __shared__ float qkbs[HEADSn];

    const int tid  = threadIdx.x;
    const int bt   = blockIdx.x;          // t-tile 0..127
    const int b    = blockIdx.y;
    const int lane = tid & 63;
    const int w    = tid >> 6;            // wave 0..3
    const int r    = lane & 15;
    const int qq   = lane >> 4;           // quarter-wave 0..3

    const __bf16* bfr   = (const __bf16*)(ws + WS_BF16);
    const __bf16* qkwB  = bfr + b*16*Cn;
    const __bf16* WvB   = bfr + 65536;
    const __bf16* projB = bfr + 131072;

    // ---- phase 0: per-batch params ----
    gml[tid] = ws[WS_G + b*Cn + tid];
    hml[tid] = ws[WS_H + b*Cn + tid];
    vbs[tid] = kv_b[HIDn + tid];
    pbs[tid] = proj_b[tid];
    if (tid < HEADSn*2) rpes[tid>>1][tid&1] = rpe[tid];
    if (tid >= 32 && tid < 32+HEADSn) qkbs[tid-32] = ws[WS_QKB + b*HEADSn + (tid-32)];

    // ---- phase 1: LN stats (fp32, coalesced: lanes = consecutive t) ----
    const int t = lane;            // 0..63 within tile
    const float* xb = x + ((size_t)b*Cn + (size_t)w*64)*Tn + (size_t)bt*TW + t;
    {
        float s = 0.f, sq = 0.f;
        for (int j = 0; j < 64; ++j) {
            float v = xb[(size_t)j*Tn];
            s += v; sq += v*v;
        }
        red1[w][t] = s; red2[w][t] = sq;
    }
    __syncthreads();
    if (tid < 64) {
        float ss = red1[0][tid]+red1[1][tid]+red1[2][tid]+red1[3][tid];
        float qq2 = red2[0][tid]+red2[1][tid]+red2[2][tid]+red2[3][tid];
        float mean = ss * (1.f/Cn);
        float var  = qq2 * (1.f/Cn) - mean*mean;
        ms[tid]  = mean;
        is_[tid] = rsqrtf(var + 1e-6f);
    }
    __syncthreads();

    // ---- phase 2: normalize + FiLM (fp32) -> bf16 xmT (L2-hot re-read) ----
    {
        float mu = ms[t], iv = is_[t];
        for (int jb = 0; jb < 64; jb += 8) {
            bf16x8 pk;
            #pragma unroll
            for (int i = 0; i < 8; ++i) {
                int c = w*64 + jb + i;
                float v = xb[(size_t)(jb+i)*Tn];
                v = (v - mu) * iv * gml[c] + hml[c];
                pk[i] = (__bf16)v;
            }
            *(bf16x8*)&xmT[t][w*64 + jb] = pk;
        }
    }
    __syncthreads();

    // ---- phase 3: logits MFMA — wave w owns t-cols [16w,16w+16) ----
    {
        f32x4 accL = {0.f,0.f,0.f,0.f};
        for (int k0 = 0; k0 < 8; ++k0) {
            bf16x8 a = *(const bf16x8*)&qkwB[(size_t)r*Cn + k0*32 + qq*8];
            bf16x8 bb = *(const bf16x8*)&xmT[w*16 + r][k0*32 + qq*8];
            accL = __builtin_amdgcn_mfma_f32_16x16x32_bf16(a, bb, accL, 0, 0, 0);
        }
        if (qq < 2) {
            #pragma unroll
            for (int rr = 0; rr < 4; ++rr)
                lg[qq*4 + rr][w*16 + r] = accL[rr];   // rows 0..7 = heads
        }
    }
    __syncthreads();

    // ---- phase 4: pairwise softmax (K=2), fp32 ----
    {
        int h = tid >> 5, u = tid & 31;
        const float sc = 0.17677669529663687f;   // 1/sqrt(32)
        float qk = qkbs[h];
        float l0 = (lg[h][2*u]   + qk)*sc + rpes[h][0];
        float l1 = (lg[h][2*u+1] + qk)*sc + rpes[h][1];
        float m = fmaxf(l0, l1);
        float e0 = __expf(l0-m), e1 = __expf(l1-m);
        float inv = 1.f / (e0 + e1);
        aw[h][2*u]   = e0*inv;
        aw[h][2*u+1] = e1*inv;
    }
    __syncthreads();

    // ---- phase 5: V-GEMM via MFMA. wave w owns d-rows [64w, 64w+64) ----
    f32x4 acc[4][4];
    #pragma unroll
    for (int m = 0; m < 4; ++m)
        #pragma unroll
        for (int n = 0; n < 4; ++n) acc[m][n] = (f32x4){0.f,0.f,0.f,0.f};
    const int d0 = w*64;
    for (int k0 = 0; k0 < 8; ++k0) {
        bf16x8 bb[4];
        #pragma unroll
        for (int n = 0; n < 4; ++n)
            bb[n] = *(const bf16x8*)&xmT[n*16 + r][k0*32 + qq*8];
        #pragma unroll
        for (int m = 0; m < 4; ++m) {
            bf16x8 a = *(const bf16x8*)&WvB[(size_t)(d0 + m*16 + r)*Cn + k0*32 + qq*8];
            #pragma unroll
            for (int n = 0; n < 4; ++n)
                acc[m][n] = __builtin_amdgcn_mfma_f32_16x16x32_bf16(a, bb[n], acc[m][n], 0, 0, 0);
        }
    }

    // ---- phase 6: attn combine (K=2) + write bf16 oT[t2][d] ----
    {
        #pragma unroll
        for (int m = 0; m < 4; ++m) {
            int dbase = d0 + m*16 + qq*4;       // 4 consecutive d per lane
            int h = dbase >> 5;
            #pragma unroll
            for (int n = 0; n < 4; ++n) {
                int tl = n*16 + r;              // this lane's t within tile
                float a0 = aw[h][tl & ~1], a1 = aw[h][tl | 1];
                bf16x4 ov;
                #pragma unroll
                for (int rr = 0; rr < 4; ++rr) {
                    float v  = acc[m][n][rr];
                    float vo = __shfl_xor(v, 1);    // partner column
                    float vb = vbs[dbase + rr];
                    float o  = a0*(v + vb) + a1*(vo + vb);  // valid on even lanes
                    ov[rr] = (__bf16)o;
                }
                if (!(r & 1)) {
                    int u = n*8 + (r >> 1);     // t2 within tile, 0..31
                    *(bf16x4*)&oT[u][dbase] = ov;
                }
            }
        }
    }
    __syncthreads();

    // ---- phase 7: proj GEMM via MFMA. wave w owns e-rows [64w, 64w+64) ----
    f32x4 acc2[4][2];
    #pragma unroll
    for (int m = 0; m < 4; ++m) { acc2[m][0] = (f32x4){0.f,0.f,0.f,0.f};
                                  acc2[m][1] = (f32x4){0.f,0.f,0.f,0.f}; }
    for (int k0 = 0; k0 < 8; ++k0) {
        bf16x8 bb[2];
        #pragma unroll
        for (int n2 = 0; n2 < 2; ++n2)
            bb[n2] = *(const bf16x8*)&oT[n2*16 + r][k0*32 + qq*8];
        #pragma unroll
        for (int m = 0; m < 4; ++m) {
            bf16x8 a = *(const bf16x8*)&projB[(size_t)(d0 + m*16 + r)*Cn + k0*32 + qq*8];
            #pragma unroll
            for (int n2 = 0; n2 < 2; ++n2)
                acc2[m][n2] = __builtin_amdgcn_mfma_f32_16x16x32_bf16(a, bb[n2], acc2[m][n2], 0, 0, 0);
        }
    }

    // ---- epilogue: bias + store fp32 ----
    {
        float* ob = out + (size_t)b*HIDn*T2n + (size_t)bt*32;
        #pragma unroll
        for (int m = 0; m < 4; ++m) {
            #pragma unroll
            for (int n2 = 0; n2 < 2; ++n2) {
                #pragma unroll
                for (int rr = 0; rr < 4; ++rr) {
                    int e = d0 + m*16 + qq*4 + rr;
                    ob[(size_t)e*T2n + n2*16 + r] = acc2[m][n2][rr] + pbs[e];
                }
            }
        }
    }
}

extern "C" void kernel_launch(void* const* d_in, const int* in_sizes, int n_in,
                              void* d_out, int out_size, void* d_ws, size_t ws_size,
                              hipStream_t stream) {
    (void)in_sizes; (void)n_in; (void)out_size; (void)ws_size;
    const float* x      = (const float*)d_in[0];
    const float* temb   = (const float*)d_in[1];
    const float* ln_w   = (const float*)d_in[2];
    const float* ln_b   = (const float*)d_in[3];
    const float* ss_w   = (const float*)d_in[4];
    const float* ss_b   = (const float*)d_in[5];
    const float* kv_w   = (const float*)d_in[6];
    const float* kv_b   = (const float*)d_in[7];
    const float* q      = (const float*)d_in[8];
    const float* qt_w   = (const float*)d_in[9];
    const float* qt_b   = (const float*)d_in[10];
    const float* rpe    = (const float*)d_in[11];
    const float* proj_w = (const float*)d_in[12];
    const float* proj_b = (const float*)d_in[13];
    float* ws  = (float*)d_ws;
    float* out = (float*)d_out;

    prep_kernel<<<dim3(Bn + 64), dim3(256), 0, stream>>>(
        temb, ln_w, ln_b, ss_w, ss_b, kv_w, kv_b, q, qt_w, qt_b, proj_w, ws);
    qna_main<<<dim3(Tn/TW, Bn), dim3(256), 0, stream>>>(
        x, kv_b, rpe, proj_b, ws, out);
}

// Round 5
// 155.946 us; speedup vs baseline: 4.5617x; 1.1154x over previous
//
#include <hip/hip_runtime.h>
#include <hip/hip_bf16.h>

#define Bn 16
#define Cn 256
#define Tn 8192
#define TFn 512
#define HIDn 256
#define HEADSn 8
#define HDn 32
#define T2n (Tn/2)
#define TW 64
#define XPAD 264   // bf16 row stride: 528 B = 132 dwords == 4 (mod 32) -> ~2-way max on b128 reads

// ws float-index layout:
//   WS_G    g[16][256]
//   WS_H    hh[16][256]
//   WS_QKB  qkb[16][8]
//   WS_BF16 (as __bf16*): qkwB[16][16][256] | WvB[256][256] | projB[256][256]
#define WS_G 0
#define WS_H 4096
#define WS_QKB 8192
#define WS_BF16 8320

typedef __attribute__((ext_vector_type(8))) __bf16 bf16x8;
typedef __attribute__((ext_vector_type(4))) __bf16 bf16x4;
typedef __attribute__((ext_vector_type(4))) float f32x4;

__global__ __launch_bounds__(256)
void prep_kernel(const float* __restrict__ temb,
                 const float* __restrict__ ln_w, const float* __restrict__ ln_b,
                 const float* __restrict__ ss_w, const float* __restrict__ ss_b,
                 const float* __restrict__ kv_w, const float* __restrict__ kv_b,
                 const float* __restrict__ qw,  const float* __restrict__ qt_w,
                 const float* __restrict__ qt_b, const float* __restrict__ proj_w,
                 float* __restrict__ ws)
{
    __bf16* bfr = (__bf16*)(ws + WS_BF16);
    const int tid = threadIdx.x;

    if (blockIdx.x >= Bn) {
        // ---- weight bf16 conversion: Wv (kv_w rows 256..511) then proj_w ----
        int cb = blockIdx.x - Bn;                       // 0..63
        size_t base = (size_t)cb*2048 + (size_t)tid*8;  // 64*2048 = 131072 elements
        const float* src = (base < 65536) ? (kv_w + 65536 + base)
                                          : (proj_w + (base - 65536));
        __bf16* dst = bfr + 65536 + base;               // WvB @65536, projB @131072
        bf16x8 o;
        #pragma unroll
        for (int i = 0; i < 8; ++i) o[i] = (__bf16)src[i];
        *(bf16x8*)dst = o;
        return;
    }

    const int b = blockIdx.x;
    __shared__ float st[TFn];
    __shared__ float qbs[HIDn];
    for (int i = tid; i < TFn; i += 256) {
        float v = temb[b*TFn + i];
        st[i] = v / (1.f + __expf(-v));   // silu
    }
    __syncthreads();
    const float4* stv = (const float4*)st;
    const float4* wS = (const float4*)(ss_w + (size_t)tid*TFn);
    const float4* wC = (const float4*)(ss_w + (size_t)(Cn+tid)*TFn);
    const float4* wQ = (const float4*)(qt_w + (size_t)tid*TFn);
    float aS=0.f, aC=0.f, aQ=0.f;
    for (int k = 0; k < TFn/4; ++k) {
        float4 s = stv[k], a = wS[k], c = wC[k], q4 = wQ[k];
        aS += s.x*a.x + s.y*a.y + s.z*a.z + s.w*a.w;
        aC += s.x*c.x + s.y*c.y + s.z*c.z + s.w*c.w;
        aQ += s.x*q4.x + s.y*q4.y + s.z*q4.z + s.w*q4.w;
    }
    float shift = aS + ss_b[tid];
    float scale = aC + ss_b[Cn + tid];
    float qb = qw[tid] + aQ + qt_b[tid];
    qbs[tid] = qb;
    float sc1 = 1.f + scale;
    ws[WS_G + b*Cn + tid] = ln_w[tid] * sc1;                 // g
    ws[WS_H + b*Cn + tid] = ln_b[tid] * sc1 + shift;         // hh
    __syncthreads();
    // qkwB[b][h][c] bf16, rows 8..15 zero-padded for MFMA M=16
    __bf16* qkwB = bfr + b*16*Cn;
    for (int idx = tid; idx < 16*Cn; idx += 256) {
        int h = idx >> 8, c = idx & 255;
        float acc = 0.f;
        if (h < HEADSn) {
            #pragma unroll
            for (int d = 0; d < HDn; ++d)
                acc += qbs[h*HDn + d] * kv_w[(size_t)(h*HDn + d)*Cn + c];
        }
        qkwB[idx] = (__bf16)acc;
    }
    if (tid < HEADSn) {
        float acc = 0.f;
        #pragma unroll
        for (int d = 0; d < HDn; ++d) acc += qbs[tid*HDn + d]*kv_b[tid*HDn + d];
        ws[WS_QKB + b*HEADSn + tid] = acc;
    }
}

__global__ __launch_bounds__(256, 3)
void qna_main(const float* __restrict__ x,
              const float* __restrict__ kv_b, const float* __restrict__ rpe,
              const float* __restrict__ proj_b,
              const float* __restrict__ ws, float* __restrict__ out)
{
    __shared__ __bf16 xmT[TW][XPAD];        // 33792 B; reused for oT[32][XPAD] after V-GEMM
    __shared__ float gml[Cn], hml[Cn], vbs[Cn], pbs[Cn];
    __shared__ float4 red1_4[4][16], red2_4[4][16];
    __shared__ float ms[64], is_[64];
    __shared__ float lg[HEADSn][TW];
    __shared__ float aw[HEADSn][TW];
    __shared__ float rpes[HEADSn][2];
    __shared__ float qkbs[HEADSn];

    const int tid  = threadIdx.x;
    const int bt   = blockIdx.x;          // t-tile 0..127
    const int b    = blockIdx.y;
    const int lane = tid & 63;
    const int w    = tid >> 6;            // wave 0..3
    const int r    = lane & 15;
    const int qq   = lane >> 4;           // quarter-wave 0..3

    const __bf16* bfr   = (const __bf16*)(ws + WS_BF16);
    const __bf16* qkwB  = bfr + b*16*Cn;
    const __bf16* WvB   = bfr + 65536;
    const __bf16* projB = bfr + 131072;

    // ---- phase 0: per-batch params ----
    gml[tid] = ws[WS_G + b*Cn + tid];
    hml[tid] = ws[WS_H + b*Cn + tid];
    vbs[tid] = kv_b[HIDn + tid];
    pbs[tid] = proj_b[tid];
    if (tid < HEADSn*2) rpes[tid>>1][tid&1] = rpe[tid];
    if (tid >= 32 && tid < 32+HEADSn) qkbs[tid-32] = ws[WS_QKB + b*HEADSn + (tid-32)];

    // ---- phase 1: load x-tile to REGISTERS (float4), LN stats in-wave ----
    const int tq  = lane & 15;            // t-quad: owns t = tq*4 .. tq*4+3
    const int rgl = lane >> 4;            // row-group within wave, 0..3
    const int c0  = w*64 + rgl*16;        // first channel row of this thread
    const float* xb = x + ((size_t)b*Cn + c0)*Tn + (size_t)bt*TW + tq*4;
    float4 xr[16];
    #pragma unroll
    for (int j = 0; j < 16; ++j)
        xr[j] = *(const float4*)&xb[(size_t)j*Tn];
    {
        float4 s4 = {0,0,0,0}, q4 = {0,0,0,0};
        #pragma unroll
        for (int j = 0; j < 16; ++j) {
            s4.x += xr[j].x; s4.y += xr[j].y; s4.z += xr[j].z; s4.w += xr[j].w;
            q4.x += xr[j].x*xr[j].x; q4.y += xr[j].y*xr[j].y;
            q4.z += xr[j].z*xr[j].z; q4.w += xr[j].w*xr[j].w;
        }
        // reduce across rgl (lane bits 4,5) within the wave
        #pragma unroll
        for (int off = 16; off < 64; off <<= 1) {
            s4.x += __shfl_xor(s4.x, off); s4.y += __shfl_xor(s4.y, off);
            s4.z += __shfl_xor(s4.z, off); s4.w += __shfl_xor(s4.w, off);
            q4.x += __shfl_xor(q4.x, off); q4.y += __shfl_xor(q4.y, off);
            q4.z += __shfl_xor(q4.z, off); q4.w += __shfl_xor(q4.w, off);
        }
        if (rgl == 0) { red1_4[w][tq] = s4; red2_4[w][tq] = q4; }
    }
    __syncthreads();
    if (tid < 64) {
        int tq2 = tid >> 2, k = tid & 3;
        float s = 0.f, sq = 0.f;
        #pragma unroll
        for (int ww = 0; ww < 4; ++ww) {
            s  += ((const float*)&red1_4[ww][tq2])[k];
            sq += ((const float*)&red2_4[ww][tq2])[k];
        }
        float mean = s * (1.f/Cn);
        float var  = sq * (1.f/Cn) - mean*mean;
        ms[tid]  = mean;
        is_[tid] = rsqrtf(var + 1e-6f);
    }
    __syncthreads();

    // ---- phase 2: normalize + FiLM from registers -> bf16 xmT[t][c] ----
    {
        #define DO_K(K, COMP) { \
            float mu = ms[tq*4+K], iv = is_[tq*4+K]; \
            bf16x8 p0, p1; \
            _Pragma("unroll") \
            for (int j = 0; j < 8; ++j) { int c = c0 + j; \
                p0[j] = (__bf16)((xr[j].COMP - mu)*iv*gml[c] + hml[c]); } \
            _Pragma("unroll") \
            for (int j = 0; j < 8; ++j) { int c = c0 + 8 + j; \
                p1[j] = (__bf16)((xr[8+j].COMP - mu)*iv*gml[c] + hml[c]); } \
            *(bf16x8*)&xmT[tq*4+K][c0]     = p0; \
            *(bf16x8*)&xmT[tq*4+K][c0 + 8] = p1; }
        DO_K(0, x) DO_K(1, y) DO_K(2, z) DO_K(3, w)
        #undef DO_K
    }
    __syncthreads();

    // ---- phase 3: logits MFMA — wave w owns t-cols [16w,16w+16) ----
    {
        f32x4 accL = {0.f,0.f,0.f,0.f};
        for (int k0 = 0; k0 < 8; ++k0) {
            bf16x8 a = *(const bf16x8*)&qkwB[(size_t)r*Cn + k0*32 + qq*8];
            bf16x8 bb = *(const bf16x8*)&xmT[w*16 + r][k0*32 + qq*8];
            accL = __builtin_amdgcn_mfma_f32_16x16x32_bf16(a, bb, accL, 0, 0, 0);
        }
        if (qq < 2) {
            #pragma unroll
            for (int rr = 0; rr < 4; ++rr)
                lg[qq*4 + rr][w*16 + r] = accL[rr];   // rows 0..7 = heads
        }
    }
    __syncthreads();

    // ---- phase 4 (folded): pairwise softmax, hides under V-GEMM loads ----
    {
        int h = tid >> 5, u = tid & 31;
        const float sc = 0.17677669529663687f;   // 1/sqrt(32)
        float qk = qkbs[h];
        float l0 = (lg[h][2*u]   + qk)*sc + rpes[h][0];
        float l1 = (lg[h][2*u+1] + qk)*sc + rpes[h][1];
        float m = fmaxf(l0, l1);
        float e0 = __expf(l0-m), e1 = __expf(l1-m);
        float inv = 1.f / (e0 + e1);
        aw[h][2*u]   = e0*inv;
        aw[h][2*u+1] = e1*inv;
    }

    // ---- phase 5: V-GEMM via MFMA. wave w owns d-rows [64w, 64w+64) ----
    f32x4 acc[4][4];
    #pragma unroll
    for (int m = 0; m < 4; ++m)
        #pragma unroll
        for (int n = 0; n < 4; ++n) acc[m][n] = (f32x4){0.f,0.f,0.f,0.f};
    const int d0 = w*64;
    for (int k0 = 0; k0 < 8; ++k0) {
        bf16x8 bb[4];
        #pragma unroll
        for (int n = 0; n < 4; ++n)
            bb[n] = *(const bf16x8*)&xmT[n*16 + r][k0*32 + qq*8];
        #pragma unroll
        for (int m = 0; m < 4; ++m) {
            bf16x8 a = *(const bf16x8*)&WvB[(size_t)(d0 + m*16 + r)*Cn + k0*32 + qq*8];
            #pragma unroll
            for (int n = 0; n < 4; ++n)
                acc[m][n] = __builtin_amdgcn_mfma_f32_16x16x32_bf16(a, bb[n], acc[m][n], 0, 0, 0);
        }
    }
    __syncthreads();   // all xmT reads + aw writes done

    // ---- phase 6: attn combine (K=2) + write bf16 oT (union with xmT) ----
    __bf16* oTp = &xmT[0][0];           // oT[u][d] at stride XPAD, u<32
    {
        const int t0 = 0;  (void)t0;
        #pragma unroll
        for (int m = 0; m < 4; ++m) {
            int dbase = d0 + m*16 + qq*4;       // 4 consecutive d per lane
            int h = dbase >> 5;
            #pragma unroll
            for (int n = 0; n < 4; ++n) {
                int tl = n*16 + r;              // this lane's t within tile
                float a0 = aw[h][tl & ~1], a1 = aw[h][tl | 1];
                bf16x4 ov;
                #pragma unroll
                for (int rr = 0; rr < 4; ++rr) {
                    float v  = acc[m][n][rr];
                    float vo = __shfl_xor(v, 1);    // partner column
                    float vb = vbs[dbase + rr];
                    float o  = a0*(v + vb) + a1*(vo + vb);  // valid on even lanes
                    ov[rr] = (__bf16)o;
                }
                if (!(r & 1)) {
                    int u = n*8 + (r >> 1);     // t2 within tile, 0..31
                    *(bf16x4*)&oTp[(size_t)u*XPAD + dbase] = ov;
                }
            }
        }
    }
    __syncthreads();

    // ---- phase 7: proj GEMM via MFMA. wave w owns e-rows [64w, 64w+64) ----
    f32x4 acc2[4][2];
    #pragma unroll
    for (int m = 0; m < 4; ++m) { acc2[m][0] = (f32x4){0.f,0.f,0.f,0.f};
                                  acc2[m][1] = (f32x4){0.f,0.f,0.f,0.f}; }
    for (int k0 = 0; k0 < 8; ++k0) {
        bf16x8 bb[2];
        #pragma unroll
        for (int n2 = 0; n2 < 2; ++n2)
            bb[n2] = *(const bf16x8*)&oTp[(size_t)(n2*16 + r)*XPAD + k0*32 + qq*8];
        #pragma unroll
        for (int m = 0; m < 4; ++m) {
            bf16x8 a = *(const bf16x8*)&projB[(size_t)(d0 + m*16 + r)*Cn + k0*32 + qq*8];
            #pragma unroll
            for (int n2 = 0; n2 < 2; ++n2)
                acc2[m][n2] = __builtin_amdgcn_mfma_f32_16x16x32_bf16(a, bb[n2], acc2[m][n2], 0, 0, 0);
        }
    }

    // ---- epilogue: bias + store fp32 ----
    {
        float* ob = out + (size_t)b*HIDn*T2n + (size_t)bt*32;
        #pragma unroll
        for (int m = 0; m < 4; ++m) {
            #pragma unroll
            for (int n2 = 0; n2 < 2; ++n2) {
                #pragma unroll
                for (int rr = 0; rr < 4; ++rr) {
                    int e = d0 + m*16 + qq*4 + rr;
                    ob[(size_t)e*T2n + n2*16 + r] = acc2[m][n2][rr] + pbs[e];
                }
            }
        }
    }
}

extern "C" void kernel_launch(void* const* d_in, const int* in_sizes, int n_in,
                              void* d_out, int out_size, void* d_ws, size_t ws_size,
                              hipStream_t stream) {
    (void)in_sizes; (void)n_in; (void)out_size; (void)ws_size;
    const float* x      = (const float*)d_in[0];
    const float* temb   = (const float*)d_in[1];
    const float* ln_w   = (const float*)d_in[2];
    const float* ln_b   = (const float*)d_in[3];
    const float* ss_w   = (const float*)d_in[4];
    const float* ss_b   = (const float*)d_in[5];
    const float* kv_w   = (const float*)d_in[6];
    const float* kv_b   = (const float*)d_in[7];
    const float* q      = (const float*)d_in[8];
    const float* qt_w   = (const float*)d_in[9];
    const float* qt_b   = (const float*)d_in[10];
    const float* rpe    = (const float*)d_in[11];
    const float* proj_w = (const float*)d_in[12];
    const float* proj_b = (const float*)d_in[13];
    float* ws  = (float*)d_ws;
    float* out = (float*)d_out;

    prep_kernel<<<dim3(Bn + 64), dim3(256), 0, stream>>>(
        temb, ln_w, ln_b, ss_w, ss_b, kv_w, kv_b, q, qt_w, qt_b, proj_w, ws);
    qna_main<<<dim3(Tn/TW, Bn), dim3(256), 0, stream>>>(
        x, kv_b, rpe, proj_b, ws, out);
}